// Round 10
// baseline (68.008 us; speedup 1.0000x reference)
//
#include <hip/hip_runtime.h>
#include <hip/hip_bf16.h>

// PositionAwareARCEncoder fused kernels.
// B=32768, H=W=5, NC=4, E=64, HID=128, OUT=128, NH=4, HD=16.
//
// R9: 2-launch prep chain + arc_fused at grid 1024 (2 tiles/block, 4 blocks/CU).
//  prepA (210 blocks): per-cij MLPs -> inpval/outval; plus independent tables
//    qtab, cpeproj, bias1, wovT (computed direct from o_w@cb_w1), cbw2T.
//  prepM (102 blocks): per-cij: k-col -> stab slice; v-col -> vtabT (bf16,
//    k'=4*ij+ig layout); outproj-col -> outprojBT. Aux: cpe/bias rows + zeros.
//  arc_fused: persistent 2-tile blocks, B-frags hoisted to registers once,
//    one-hot W/OG scatter (no zeroing), 3 barriers/tile, obs prefetch.

typedef __attribute__((ext_vector_type(8))) short short8v;
typedef __attribute__((ext_vector_type(4))) float float4v;

static __device__ __forceinline__ short f2bfs(float f) {
  __hip_bfloat16 h = __float2bfloat16(f);   // native cvt, RNE
  return *reinterpret_cast<short*>(&h);
}
static __device__ __forceinline__ float bfs2f(short s) {
  return __uint_as_float(((unsigned)(unsigned short)s) << 16);
}
static __device__ __forceinline__ unsigned short f2bf(float f) {
  unsigned int u = __float_as_uint(f);
  unsigned int r = (u + 0x7fffu + ((u >> 16) & 1u)) >> 16;
  return (unsigned short)r;
}

// ---------------- prepA: MLPs + all tables independent of MLP outputs ----
__global__ __launch_bounds__(128) void prepA(
    const float* __restrict__ color_embed, const float* __restrict__ row_embed,
    const float* __restrict__ col_embed,
    const float* __restrict__ ip_w1, const float* __restrict__ ip_b1,
    const float* __restrict__ ip_w2, const float* __restrict__ ip_b2,
    const float* __restrict__ op_w1, const float* __restrict__ op_b1,
    const float* __restrict__ op_w2, const float* __restrict__ op_b2,
    const float* __restrict__ q_w, const float* __restrict__ q_b,
    const float* __restrict__ o_w, const float* __restrict__ o_b,
    const float* __restrict__ cb_w1, const float* __restrict__ cb_b1,
    const float* __restrict__ cb_w2,
    float* __restrict__ inpval, float* __restrict__ outval,
    float* __restrict__ qtab, float* __restrict__ cpeproj,
    float* __restrict__ bias1,
    unsigned short* __restrict__ wovT, unsigned short* __restrict__ cbw2T) {
  const int bid = blockIdx.x, t = threadIdx.x;
  if (bid < 200) {                         // MLP for cij (input / output path)
    __shared__ float feat[128];
    __shared__ float h1[128];
    const int path = bid / 100;
    const int cij = bid % 100;
    const int c = cij / 25, ij = cij % 25, gi = ij / 5, gj = ij % 5;
    if (t < 64)      feat[t] = color_embed[c * 64 + t];
    else if (t < 96) feat[t] = row_embed[gi * 32 + (t - 64)];
    else             feat[t] = col_embed[gj * 32 + (t - 96)];
    __syncthreads();
    const float* w1 = path ? op_w1 : ip_w1;
    const float* b1 = path ? op_b1 : ip_b1;
    float acc = b1[t];
#pragma unroll 8
    for (int d = 0; d < 128; ++d) acc = fmaf(feat[d], w1[d * 128 + t], acc);
    h1[t] = fmaxf(acc, 0.f);
    __syncthreads();
    if (t < 64) {
      const float* w2 = path ? op_w2 : ip_w2;
      const float* b2 = path ? op_b2 : ip_b2;
      float v = b2[t];
#pragma unroll 8
      for (int d = 0; d < 128; ++d) v = fmaf(h1[d], w2[d * 64 + t], v);
      (path ? outval : inpval)[cij * 64 + t] = v;
    }
  } else if (bid == 200) {                 // qtab[26][64] + bias1[128]
    for (int i = t; i < 1664; i += 128) {
      const int p = i >> 6, e2 = i & 63;
      float a = q_b[e2];
      if (p < 25) {
        const int r = p / 5, cc = p % 5;
#pragma unroll 8
        for (int e = 0; e < 32; ++e) a = fmaf(row_embed[r * 32 + e], q_w[e * 64 + e2], a);
#pragma unroll 8
        for (int e = 0; e < 32; ++e) a = fmaf(col_embed[cc * 32 + e], q_w[(32 + e) * 64 + e2], a);
      }
      qtab[i] = a;
    }
    float a = cb_b1[t];
#pragma unroll 8
    for (int e = 0; e < 64; ++e) a = fmaf(o_b[e], cb_w1[e * 128 + t], a);
    bias1[t] = a;
  } else if (bid == 201) {                 // cpeproj[26][128]
    for (int i = t; i < 3328; i += 128) {
      const int p = i >> 7, jj = i & 127;
      float a = 0.f;
      if (p < 25) {
        const int r = p / 5, cc = p % 5;
#pragma unroll 8
        for (int e = 0; e < 32; ++e) a = fmaf(row_embed[r * 32 + e], cb_w1[(128 + e) * 128 + jj], a);
#pragma unroll 8
        for (int e = 0; e < 32; ++e) a = fmaf(col_embed[cc * 32 + e], cb_w1[(160 + e) * 128 + jj], a);
      }
      cpeproj[i] = a;
    }
  } else if (bid < 206) {                  // wovT[col 128][d 64] direct
    const int base = (bid - 202) * 2048;
    for (int i = t; i < 2048; i += 128) {
      const int idx = base + i, col = idx >> 6, d = idx & 63;
      float a = 0.f;
#pragma unroll 8
      for (int e = 0; e < 64; ++e) a = fmaf(o_w[d * 64 + e], cb_w1[e * 128 + col], a);
      wovT[idx] = f2bf(a);
    }
  } else {                                 // bid 206..209: cbw2T[col 128][k 128]
    const int base = (bid - 206) * 4096;
    for (int i = t; i < 4096; i += 128) {
      const int idx = base + i, col = idx >> 7, k = idx & 127;
      cbw2T[idx] = f2bf(cb_w2[k * 128 + col]);
    }
  }
}

// ---------------- prepM: per-cij k/v/outproj + stab; aux rows --------------
__global__ __launch_bounds__(128) void prepM(
    const float* __restrict__ k_w, const float* __restrict__ k_b,
    const float* __restrict__ v_w, const float* __restrict__ v_b,
    const float* __restrict__ cb_w1,
    const float* __restrict__ qtab, const float* __restrict__ cpeproj,
    const float* __restrict__ bias1,
    const float* __restrict__ inpval, const float* __restrict__ outval,
    float* __restrict__ stab, unsigned short* __restrict__ vtabT,
    unsigned short* __restrict__ outprojBT) {
  const int bid = blockIdx.x, t = threadIdx.x;
  if (bid < 100) {
    __shared__ float kk[64];
    const int ig = bid / 25, ij = bid % 25;   // color, cell
    const float* x = inpval + bid * 64;
    if (t < 64) {                            // ktab column -> LDS
      float a = k_b[t];
#pragma unroll 8
      for (int e = 0; e < 64; ++e) a = fmaf(x[e], k_w[e * 64 + t], a);
      kk[t] = a;
    } else {                                 // vtab column -> vtabT direct
      const int e2 = t - 64;
      float a = v_b[e2];
#pragma unroll 8
      for (int e = 0; e < 64; ++e) a = fmaf(x[e], v_w[e * 64 + e2], a);
      vtabT[(e2 >> 4) * 2048 + (e2 & 15) * 128 + 4 * ij + ig] = f2bf(a);
    }
    __syncthreads();
    {                                        // outproj column -> outprojBT direct
      const float* y = outval + bid * 64;
      float a = 0.f;
#pragma unroll 8
      for (int e = 0; e < 64; ++e) a = fmaf(y[e], cb_w1[(64 + e) * 128 + t], a);
      outprojBT[t * 128 + 4 * ij + ig] = f2bf(a * (1.f / 25.f));
    }
    if (t < 104) {                           // stab slice for this (ig, ij)
      const int cpe = t >> 2, h = t & 3;
      const float* qq = qtab + cpe * 64 + h * 16;
      float a = 0.f;
#pragma unroll
      for (int d = 0; d < 16; ++d) a = fmaf(qq[d], kk[h * 16 + d], a);
      stab[cpe * 400 + ig * 100 + ij * 4 + h] = a * 0.25f;
    }
  } else if (bid == 100) {                   // outprojBT aux rows 100..127
    for (int p = 0; p < 26; ++p)
      outprojBT[t * 128 + 100 + p] = f2bf(cpeproj[p * 128 + t]);
    outprojBT[t * 128 + 126] = f2bf(bias1[t]);
    outprojBT[t * 128 + 127] = 0;
  } else {                                   // zero vtabT k' rows 100..127
    for (int i = t; i < 1792; i += 128) {
      const int h = i / 448, r = i % 448;
      const int d = r / 28, kp = 100 + r % 28;
      vtabT[h * 2048 + d * 128 + kp] = 0;
    }
  }
}

__global__ __launch_bounds__(256) void arc_fused(
    const int* __restrict__ obs,
    const float* __restrict__ stab,
    const unsigned short* __restrict__ vtabT,
    const unsigned short* __restrict__ outprojBT,
    const unsigned short* __restrict__ wovT,
    const unsigned short* __restrict__ cbw2T,
    const float* __restrict__ cb_b2,
    float* __restrict__ out) {
  __shared__ __align__(16) short lds_w[4 * 16 * 128];    // 16 KB, swz by batch row
  __shared__ __align__(16) short lds_og[16 * 128];       // 4 KB
  __shared__ __align__(16) short lds_raH[16 * 64];       // 2 KB
  __shared__ __align__(16) short lds_hidH[16 * 128];     // 4 KB
  __shared__ __align__(16) short lds_hidL[16 * 128];     // 4 KB
  // 30 KB; grid 1024 -> 4 blocks/CU resident (16 waves/CU)

  const int tid = threadIdx.x;
  const int lane = tid & 63, wv = tid >> 6;
  const int row16 = lane & 15, g4 = lane >> 4;
  const int hh = row16 >> 2, jj = row16 & 3;
  const int b_loc = wv * 4 + g4;
  const int rsw = (row16 & 7) << 4;
  const int bswz = (b_loc & 7) << 4;
  const int bbase = blockIdx.x * 32;

  // ---- hoist all B-fragments into registers (constant across tiles) ----
  short8v Bv[4], Bo[2][4], Bw[2][2], Bc[2][4];
#pragma unroll
  for (int ks = 0; ks < 4; ++ks)
    Bv[ks] = *(const short8v*)(vtabT + wv * 2048 + row16 * 128 + ks * 32 + g4 * 8);
#pragma unroll
  for (int t = 0; t < 2; ++t) {
    const int col = wv * 32 + t * 16 + row16;
#pragma unroll
    for (int ks = 0; ks < 4; ++ks) {
      Bo[t][ks] = *(const short8v*)(outprojBT + col * 128 + ks * 32 + g4 * 8);
      Bc[t][ks] = *(const short8v*)(cbw2T + col * 128 + ks * 32 + g4 * 8);
    }
#pragma unroll
    for (int ks = 0; ks < 2; ++ks)
      Bw[t][ks] = *(const short8v*)(wovT + col * 64 + ks * 32 + g4 * 8);
  }
  const float bv0 = cb_b2[wv * 32 + row16];
  const float bv1 = cb_b2[wv * 32 + 16 + row16];

  // ---- one-time zero of W (covers the never-scattered pad bytes) ----
  {
    const int4 z = {0, 0, 0, 0};
    int4* pw = (int4*)lds_w;
#pragma unroll
    for (int i = 0; i < 4; ++i) pw[tid + 256 * i] = z;
  }

  // ---- prefetch obs for tile 0 ----
  int xs[4], ys[4];
#pragma unroll
  for (int e = 0; e < 4; ++e) {
    const int* ob = obs + (bbase + wv * 4 + e) * 75;
    xs[e] = ob[lane];
    ys[e] = (lane < 11) ? ob[64 + lane] : 0;
  }
  __syncthreads();   // W zero visible to all

  for (int it = 0; it < 2; ++it) {
    const int b0 = bbase + it * 16;

    // ---- decode from prefetched obs ----
    unsigned iglo = 0, ighi = 0, oglo = 0, oghi = 0;
    int cpe_sel = 0;
#pragma unroll
    for (int e = 0; e < 4; ++e) {
      const unsigned long long blo = __ballot(xs[e] & 1);
      const unsigned long long bhi = __ballot(xs[e] & 2);
      const unsigned long long bnzy = __ballot((lane < 11) && (ys[e] != 0));
      const unsigned e_iglo = (unsigned)(blo & 0x1FFFFFFull);
      const unsigned e_ighi = (unsigned)(bhi & 0x1FFFFFFull);
      const unsigned e_oglo = (unsigned)((blo >> 25) & 0x1FFFFFFull);
      const unsigned e_oghi = (unsigned)((bhi >> 25) & 0x1FFFFFFull);
      const unsigned e_mb = (unsigned)(((blo | bhi) >> 50) | (bnzy << 14));
      const int e_cpe = e_mb ? __builtin_ctz(e_mb) : 25;
      if (g4 == e) { iglo = e_iglo; ighi = e_ighi; oglo = e_oglo; oghi = e_oghi; cpe_sel = e_cpe; }
    }

    // ---- softmax: thread-per-(batch, head hh, slot jj) ----
    float ev[7];
    int ig7[7];
    {
      float sv[7];
      float mx = -1e30f;
      const float* sb = stab + cpe_sel * 400 + hh;
#pragma unroll
      for (int m = 0; m < 7; ++m) {
        const int ij = jj + 4 * m;
        if (ij < 25) {
          const int ig = ((iglo >> ij) & 1) | (((ighi >> ij) & 1) << 1);
          ig7[m] = ig;
          sv[m] = sb[ig * 100 + ij * 4];
          mx = fmaxf(mx, sv[m]);
        }
      }
      mx = fmaxf(mx, __shfl_xor(mx, 1));
      mx = fmaxf(mx, __shfl_xor(mx, 2));
      float sum = 0.f;
#pragma unroll
      for (int m = 0; m < 7; ++m) {
        const int ij = jj + 4 * m;
        if (ij < 25) { ev[m] = __expf(sv[m] - mx); sum += ev[m]; }
      }
      sum += __shfl_xor(sum, 1);
      sum += __shfl_xor(sum, 2);
      const float inv = __builtin_amdgcn_rcpf(sum);
#pragma unroll
      for (int m = 0; m < 7; ++m) ev[m] *= inv;
    }

    // ---- scatter W: thread owns k' = 4*(jj+4m)+0..3 (8B each), m=0..6 ----
#pragma unroll
    for (int m = 0; m < 7; ++m) {
      const int ij = jj + 4 * m;
      unsigned u0 = 0, u1 = 0;
      if (ij < 25) {
        const unsigned pbu = (unsigned)(unsigned short)f2bfs(ev[m]);
        const int ig = ig7[m];
        u0 = (ig == 0) ? pbu : ((ig == 1) ? (pbu << 16) : 0u);
        u1 = (ig == 2) ? pbu : ((ig == 3) ? (pbu << 16) : 0u);
      }
      const int off = (hh * 4096 + b_loc * 256 + 8 * ij) ^ bswz;
      *(int2*)((char*)lds_w + off) = make_int2((int)u0, (int)u1);
    }

    // ---- scatter OG row b_loc: thread row16 owns k' = 8*row16..+8 (16B) ----
    {
      unsigned sh[8];
#pragma unroll
      for (int u = 0; u < 8; ++u) {
        const int kp = row16 * 8 + u;
        unsigned v = 0;
        if (kp < 100) {
          const int ijq = kp >> 2;
          const int og = ((oglo >> ijq) & 1) | (((oghi >> ijq) & 1) << 1);
          v = (og == (kp & 3)) ? 0x3F80u : 0u;
        } else if (kp < 126) {
          v = (cpe_sel == kp - 100) ? 0x3F80u : 0u;
        } else if (kp == 126) {
          v = 0x3F80u;
        }
        sh[u] = v;
      }
      int4 pk;
      pk.x = (int)(sh[0] | (sh[1] << 16));
      pk.y = (int)(sh[2] | (sh[3] << 16));
      pk.z = (int)(sh[4] | (sh[5] << 16));
      pk.w = (int)(sh[6] | (sh[7] << 16));
      const int off = (b_loc * 256 + row16 * 16) ^ bswz;
      *(int4*)((char*)lds_og + off) = pk;
    }
    __syncthreads();   // B1: W/OG ready

    // ---- ra-GEMM (W rows = batches, head wv) + pre-GEMM (OG rows) ----
    float4v rc = {0.f, 0.f, 0.f, 0.f};
#pragma unroll
    for (int ks = 0; ks < 4; ++ks) {
      const short8v a = *(const short8v*)((char*)lds_w +
          ((wv * 4096 + row16 * 256 + ks * 64 + g4 * 16) ^ rsw));
      rc = __builtin_amdgcn_mfma_f32_16x16x32_bf16(a, Bv[ks], rc, 0, 0, 0);
    }
    float4v acc[2];
    acc[0] = (float4v){0.f, 0.f, 0.f, 0.f};
    acc[1] = (float4v){0.f, 0.f, 0.f, 0.f};
#pragma unroll
    for (int ks = 0; ks < 4; ++ks) {
      const short8v a = *(const short8v*)((char*)lds_og +
          ((row16 * 256 + ks * 64 + g4 * 16) ^ rsw));
      acc[0] = __builtin_amdgcn_mfma_f32_16x16x32_bf16(a, Bo[0][ks], acc[0], 0, 0, 0);
      acc[1] = __builtin_amdgcn_mfma_f32_16x16x32_bf16(a, Bo[1][ks], acc[1], 0, 0, 0);
    }

    // ---- prefetch next tile's obs (hides HBM latency under MFMA phase) ----
    if (it < 1) {
#pragma unroll
      for (int e = 0; e < 4; ++e) {
        const int* ob = obs + (bbase + 16 + wv * 4 + e) * 75;
        xs[e] = ob[lane];
        ys[e] = (lane < 11) ? ob[64 + lane] : 0;
      }
    }

    // ---- ra -> LDS (hi only) ----
#pragma unroll
    for (int r = 0; r < 4; ++r) {
      const int b = g4 * 4 + r;
      const int off = (b * 128 + (wv * 16 + row16) * 2) ^ ((b & 7) << 4);
      *(short*)((char*)lds_raH + off) = f2bfs(rc[r]);
    }
    __syncthreads();   // B2: ra ready; W/OG reads done

    // ---- wov-GEMM ----
    const short8v aH0 = *(const short8v*)((char*)lds_raH + ((row16 * 128 + g4 * 16) ^ rsw));
    const short8v aH1 = *(const short8v*)((char*)lds_raH + ((row16 * 128 + 64 + g4 * 16) ^ rsw));
#pragma unroll
    for (int t = 0; t < 2; ++t) {
      acc[t] = __builtin_amdgcn_mfma_f32_16x16x32_bf16(aH0, Bw[t][0], acc[t], 0, 0, 0);
      acc[t] = __builtin_amdgcn_mfma_f32_16x16x32_bf16(aH1, Bw[t][1], acc[t], 0, 0, 0);
    }

    // ---- relu -> hidden bf16 hi+lo ----
#pragma unroll
    for (int t = 0; t < 2; ++t) {
      const int col = wv * 32 + t * 16 + row16;
#pragma unroll
      for (int rr = 0; rr < 4; ++rr) {
        const int row = g4 * 4 + rr;
        const float hv = fmaxf(acc[t][rr], 0.f);
        const short hb = f2bfs(hv);
        const int off = (row * 256 + col * 2) ^ ((row & 7) << 4);
        *(short*)((char*)lds_hidH + off) = hb;
        *(short*)((char*)lds_hidL + off) = f2bfs(hv - bfs2f(hb));
      }
    }
    __syncthreads();   // B3: hidden ready

    // ---- out-GEMM ----
    short8v ahH[4], ahL[4];
#pragma unroll
    for (int ks = 0; ks < 4; ++ks) {
      const int off = (row16 * 256 + ks * 64 + g4 * 16) ^ rsw;
      ahH[ks] = *(const short8v*)((char*)lds_hidH + off);
      ahL[ks] = *(const short8v*)((char*)lds_hidL + off);
    }
#pragma unroll
    for (int t = 0; t < 2; ++t) {
      const int col = wv * 32 + t * 16 + row16;
      float4v c2 = {0.f, 0.f, 0.f, 0.f};
#pragma unroll
      for (int ks = 0; ks < 4; ++ks) {
        c2 = __builtin_amdgcn_mfma_f32_16x16x32_bf16(ahL[ks], Bc[t][ks], c2, 0, 0, 0);
        c2 = __builtin_amdgcn_mfma_f32_16x16x32_bf16(ahH[ks], Bc[t][ks], c2, 0, 0, 0);
      }
      const float bv = t ? bv1 : bv0;
#pragma unroll
      for (int rr = 0; rr < 4; ++rr)
        out[(b0 + g4 * 4 + rr) * 128 + col] = c2[rr] + bv;
    }
  }
}

extern "C" void kernel_launch(void* const* d_in, const int* in_sizes, int n_in,
                              void* d_out, int out_size, void* d_ws, size_t ws_size,
                              hipStream_t stream) {
  const int*   obs         = (const int*)d_in[0];
  const float* color_embed = (const float*)d_in[1];
  const float* row_embed   = (const float*)d_in[2];
  const float* col_embed   = (const float*)d_in[3];
  const float* ip_w1 = (const float*)d_in[4];
  const float* ip_b1 = (const float*)d_in[5];
  const float* ip_w2 = (const float*)d_in[6];
  const float* ip_b2 = (const float*)d_in[7];
  const float* q_w = (const float*)d_in[8];
  const float* q_b = (const float*)d_in[9];
  const float* k_w = (const float*)d_in[10];
  const float* k_b = (const float*)d_in[11];
  const float* v_w = (const float*)d_in[12];
  const float* v_b = (const float*)d_in[13];
  const float* o_w = (const float*)d_in[14];
  const float* o_b = (const float*)d_in[15];
  const float* op_w1 = (const float*)d_in[16];
  const float* op_b1 = (const float*)d_in[17];
  const float* op_w2 = (const float*)d_in[18];
  const float* op_b2 = (const float*)d_in[19];
  const float* cb_w1 = (const float*)d_in[20];
  const float* cb_b1 = (const float*)d_in[21];
  const float* cb_w2 = (const float*)d_in[22];
  const float* cb_b2 = (const float*)d_in[23];

  float* ws = (float*)d_ws;
  float* qtab    = ws;                 // 1664
  float* cpeproj = qtab + 1664;        // 3328
  float* bias1   = cpeproj + 3328;     // 128
  float* stab    = bias1 + 128;        // 10400  (ends at 15520)
  unsigned short* wovT      = (unsigned short*)(ws + 15520);  //  8192 us (4096 f)
  unsigned short* cbw2T     = (unsigned short*)(ws + 19616);  // 16384 us (8192 f)
  unsigned short* vtabT     = (unsigned short*)(ws + 27808);  //  8192 us (4096 f)
  unsigned short* outprojBT = (unsigned short*)(ws + 31904);  // 16384 us (8192 f)
  float* inpval  = ws + 40096;         // 6400
  float* outval  = inpval + 6400;      // 6400
  // total 52896 floats ~= 212 KB of d_ws

  prepA<<<210, 128, 0, stream>>>(color_embed, row_embed, col_embed,
                                 ip_w1, ip_b1, ip_w2, ip_b2,
                                 op_w1, op_b1, op_w2, op_b2,
                                 q_w, q_b, o_w, o_b, cb_w1, cb_b1, cb_w2,
                                 inpval, outval, qtab, cpeproj, bias1,
                                 wovT, cbw2T);
  prepM<<<102, 128, 0, stream>>>(k_w, k_b, v_w, v_b, cb_w1,
                                 qtab, cpeproj, bias1, inpval, outval,
                                 stab, vtabT, outprojBT);
  arc_fused<<<1024, 256, 0, stream>>>(obs, stab, vtabT, outprojBT,
                                      wovT, cbw2T, cb_b2, (float*)d_out);
}

// Round 11
// 60.683 us; speedup vs baseline: 1.1207x; 1.1207x over previous
//
#include <hip/hip_runtime.h>
#include <hip/hip_bf16.h>

// PositionAwareARCEncoder fused kernels.
// B=32768, H=W=5, NC=4, E=64, HID=128, OUT=128, NH=4, HD=16.
//
// R10 = bisect: R9's 2-launch prep chain + R8's proven arc_fused shape
// (grid 512, 4 tiles of 16 batches per block, B-frags hoisted once).

typedef __attribute__((ext_vector_type(8))) short short8v;
typedef __attribute__((ext_vector_type(4))) float float4v;

static __device__ __forceinline__ short f2bfs(float f) {
  __hip_bfloat16 h = __float2bfloat16(f);   // native cvt, RNE
  return *reinterpret_cast<short*>(&h);
}
static __device__ __forceinline__ float bfs2f(short s) {
  return __uint_as_float(((unsigned)(unsigned short)s) << 16);
}
static __device__ __forceinline__ unsigned short f2bf(float f) {
  unsigned int u = __float_as_uint(f);
  unsigned int r = (u + 0x7fffu + ((u >> 16) & 1u)) >> 16;
  return (unsigned short)r;
}

// ---------------- prepA: MLPs + all tables independent of MLP outputs ----
__global__ __launch_bounds__(128) void prepA(
    const float* __restrict__ color_embed, const float* __restrict__ row_embed,
    const float* __restrict__ col_embed,
    const float* __restrict__ ip_w1, const float* __restrict__ ip_b1,
    const float* __restrict__ ip_w2, const float* __restrict__ ip_b2,
    const float* __restrict__ op_w1, const float* __restrict__ op_b1,
    const float* __restrict__ op_w2, const float* __restrict__ op_b2,
    const float* __restrict__ q_w, const float* __restrict__ q_b,
    const float* __restrict__ o_w, const float* __restrict__ o_b,
    const float* __restrict__ cb_w1, const float* __restrict__ cb_b1,
    const float* __restrict__ cb_w2,
    float* __restrict__ inpval, float* __restrict__ outval,
    float* __restrict__ qtab, float* __restrict__ cpeproj,
    float* __restrict__ bias1,
    unsigned short* __restrict__ wovT, unsigned short* __restrict__ cbw2T) {
  const int bid = blockIdx.x, t = threadIdx.x;
  if (bid < 200) {                         // MLP for cij (input / output path)
    __shared__ float feat[128];
    __shared__ float h1[128];
    const int path = bid / 100;
    const int cij = bid % 100;
    const int c = cij / 25, ij = cij % 25, gi = ij / 5, gj = ij % 5;
    if (t < 64)      feat[t] = color_embed[c * 64 + t];
    else if (t < 96) feat[t] = row_embed[gi * 32 + (t - 64)];
    else             feat[t] = col_embed[gj * 32 + (t - 96)];
    __syncthreads();
    const float* w1 = path ? op_w1 : ip_w1;
    const float* b1 = path ? op_b1 : ip_b1;
    float acc = b1[t];
#pragma unroll 8
    for (int d = 0; d < 128; ++d) acc = fmaf(feat[d], w1[d * 128 + t], acc);
    h1[t] = fmaxf(acc, 0.f);
    __syncthreads();
    if (t < 64) {
      const float* w2 = path ? op_w2 : ip_w2;
      const float* b2 = path ? op_b2 : ip_b2;
      float v = b2[t];
#pragma unroll 8
      for (int d = 0; d < 128; ++d) v = fmaf(h1[d], w2[d * 64 + t], v);
      (path ? outval : inpval)[cij * 64 + t] = v;
    }
  } else if (bid == 200) {                 // qtab[26][64] + bias1[128]
    for (int i = t; i < 1664; i += 128) {
      const int p = i >> 6, e2 = i & 63;
      float a = q_b[e2];
      if (p < 25) {
        const int r = p / 5, cc = p % 5;
#pragma unroll 8
        for (int e = 0; e < 32; ++e) a = fmaf(row_embed[r * 32 + e], q_w[e * 64 + e2], a);
#pragma unroll 8
        for (int e = 0; e < 32; ++e) a = fmaf(col_embed[cc * 32 + e], q_w[(32 + e) * 64 + e2], a);
      }
      qtab[i] = a;
    }
    float a = cb_b1[t];
#pragma unroll 8
    for (int e = 0; e < 64; ++e) a = fmaf(o_b[e], cb_w1[e * 128 + t], a);
    bias1[t] = a;
  } else if (bid == 201) {                 // cpeproj[26][128]
    for (int i = t; i < 3328; i += 128) {
      const int p = i >> 7, jj = i & 127;
      float a = 0.f;
      if (p < 25) {
        const int r = p / 5, cc = p % 5;
#pragma unroll 8
        for (int e = 0; e < 32; ++e) a = fmaf(row_embed[r * 32 + e], cb_w1[(128 + e) * 128 + jj], a);
#pragma unroll 8
        for (int e = 0; e < 32; ++e) a = fmaf(col_embed[cc * 32 + e], cb_w1[(160 + e) * 128 + jj], a);
      }
      cpeproj[i] = a;
    }
  } else if (bid < 206) {                  // wovT[col 128][d 64] direct
    const int base = (bid - 202) * 2048;
    for (int i = t; i < 2048; i += 128) {
      const int idx = base + i, col = idx >> 6, d = idx & 63;
      float a = 0.f;
#pragma unroll 8
      for (int e = 0; e < 64; ++e) a = fmaf(o_w[d * 64 + e], cb_w1[e * 128 + col], a);
      wovT[idx] = f2bf(a);
    }
  } else {                                 // bid 206..209: cbw2T[col 128][k 128]
    const int base = (bid - 206) * 4096;
    for (int i = t; i < 4096; i += 128) {
      const int idx = base + i, col = idx >> 7, k = idx & 127;
      cbw2T[idx] = f2bf(cb_w2[k * 128 + col]);
    }
  }
}

// ---------------- prepM: per-cij k/v/outproj + stab; aux rows --------------
__global__ __launch_bounds__(128) void prepM(
    const float* __restrict__ k_w, const float* __restrict__ k_b,
    const float* __restrict__ v_w, const float* __restrict__ v_b,
    const float* __restrict__ cb_w1,
    const float* __restrict__ qtab, const float* __restrict__ cpeproj,
    const float* __restrict__ bias1,
    const float* __restrict__ inpval, const float* __restrict__ outval,
    float* __restrict__ stab, unsigned short* __restrict__ vtabT,
    unsigned short* __restrict__ outprojBT) {
  const int bid = blockIdx.x, t = threadIdx.x;
  if (bid < 100) {
    __shared__ float kk[64];
    const int ig = bid / 25, ij = bid % 25;   // color, cell
    const float* x = inpval + bid * 64;
    if (t < 64) {                            // ktab column -> LDS
      float a = k_b[t];
#pragma unroll 8
      for (int e = 0; e < 64; ++e) a = fmaf(x[e], k_w[e * 64 + t], a);
      kk[t] = a;
    } else {                                 // vtab column -> vtabT direct
      const int e2 = t - 64;
      float a = v_b[e2];
#pragma unroll 8
      for (int e = 0; e < 64; ++e) a = fmaf(x[e], v_w[e * 64 + e2], a);
      vtabT[(e2 >> 4) * 2048 + (e2 & 15) * 128 + 4 * ij + ig] = f2bf(a);
    }
    __syncthreads();
    {                                        // outproj column -> outprojBT direct
      const float* y = outval + bid * 64;
      float a = 0.f;
#pragma unroll 8
      for (int e = 0; e < 64; ++e) a = fmaf(y[e], cb_w1[(64 + e) * 128 + t], a);
      outprojBT[t * 128 + 4 * ij + ig] = f2bf(a * (1.f / 25.f));
    }
    if (t < 104) {                           // stab slice for this (ig, ij)
      const int cpe = t >> 2, h = t & 3;
      const float* qq = qtab + cpe * 64 + h * 16;
      float a = 0.f;
#pragma unroll
      for (int d = 0; d < 16; ++d) a = fmaf(qq[d], kk[h * 16 + d], a);
      stab[cpe * 400 + ig * 100 + ij * 4 + h] = a * 0.25f;
    }
  } else if (bid == 100) {                   // outprojBT aux rows 100..127
    for (int p = 0; p < 26; ++p)
      outprojBT[t * 128 + 100 + p] = f2bf(cpeproj[p * 128 + t]);
    outprojBT[t * 128 + 126] = f2bf(bias1[t]);
    outprojBT[t * 128 + 127] = 0;
  } else {                                   // zero vtabT k' rows 100..127
    for (int i = t; i < 1792; i += 128) {
      const int h = i / 448, r = i % 448;
      const int d = r / 28, kp = 100 + r % 28;
      vtabT[h * 2048 + d * 128 + kp] = 0;
    }
  }
}

// ---------------- arc_fused: R8 shape verbatim (512 blocks, 4 tiles) ------
__global__ __launch_bounds__(256) void arc_fused(
    const int* __restrict__ obs,
    const float* __restrict__ stab,
    const unsigned short* __restrict__ vtabT,
    const unsigned short* __restrict__ outprojBT,
    const unsigned short* __restrict__ wovT,
    const unsigned short* __restrict__ cbw2T,
    const float* __restrict__ cb_b2,
    float* __restrict__ out) {
  __shared__ __align__(16) short lds_w[4 * 16 * 128];    // 16 KB, swz by batch row
  __shared__ __align__(16) short lds_og[16 * 128];       // 4 KB
  __shared__ __align__(16) short lds_raH[16 * 64];       // 2 KB
  __shared__ __align__(16) short lds_hidH[16 * 128];     // 4 KB
  __shared__ __align__(16) short lds_hidL[16 * 128];     // 4 KB

  const int tid = threadIdx.x;
  const int lane = tid & 63, wv = tid >> 6;
  const int row16 = lane & 15, g4 = lane >> 4;
  const int hh = row16 >> 2, jj = row16 & 3;
  const int b_loc = wv * 4 + g4;
  const int rsw = (row16 & 7) << 4;
  const int bswz = (b_loc & 7) << 4;
  const int bbase = blockIdx.x * 64;

  // ---- hoist all B-fragments into registers (constant across tiles) ----
  short8v Bv[4], Bo[2][4], Bw[2][2], Bc[2][4];
#pragma unroll
  for (int ks = 0; ks < 4; ++ks)
    Bv[ks] = *(const short8v*)(vtabT + wv * 2048 + row16 * 128 + ks * 32 + g4 * 8);
#pragma unroll
  for (int t = 0; t < 2; ++t) {
    const int col = wv * 32 + t * 16 + row16;
#pragma unroll
    for (int ks = 0; ks < 4; ++ks) {
      Bo[t][ks] = *(const short8v*)(outprojBT + col * 128 + ks * 32 + g4 * 8);
      Bc[t][ks] = *(const short8v*)(cbw2T + col * 128 + ks * 32 + g4 * 8);
    }
#pragma unroll
    for (int ks = 0; ks < 2; ++ks)
      Bw[t][ks] = *(const short8v*)(wovT + col * 64 + ks * 32 + g4 * 8);
  }
  const float bv0 = cb_b2[wv * 32 + row16];
  const float bv1 = cb_b2[wv * 32 + 16 + row16];

  // ---- one-time zero of W (covers the never-scattered pad bytes) ----
  {
    const int4 z = {0, 0, 0, 0};
    int4* pw = (int4*)lds_w;
#pragma unroll
    for (int i = 0; i < 4; ++i) pw[tid + 256 * i] = z;
  }

  // ---- prefetch obs for tile 0 ----
  int xs[4], ys[4];
#pragma unroll
  for (int e = 0; e < 4; ++e) {
    const int* ob = obs + (bbase + wv * 4 + e) * 75;
    xs[e] = ob[lane];
    ys[e] = (lane < 11) ? ob[64 + lane] : 0;
  }
  __syncthreads();   // W zero visible to all

  for (int it = 0; it < 4; ++it) {
    const int b0 = bbase + it * 16;

    // ---- decode from prefetched obs ----
    unsigned iglo = 0, ighi = 0, oglo = 0, oghi = 0;
    int cpe_sel = 0;
#pragma unroll
    for (int e = 0; e < 4; ++e) {
      const unsigned long long blo = __ballot(xs[e] & 1);
      const unsigned long long bhi = __ballot(xs[e] & 2);
      const unsigned long long bnzy = __ballot((lane < 11) && (ys[e] != 0));
      const unsigned e_iglo = (unsigned)(blo & 0x1FFFFFFull);
      const unsigned e_ighi = (unsigned)(bhi & 0x1FFFFFFull);
      const unsigned e_oglo = (unsigned)((blo >> 25) & 0x1FFFFFFull);
      const unsigned e_oghi = (unsigned)((bhi >> 25) & 0x1FFFFFFull);
      const unsigned e_mb = (unsigned)(((blo | bhi) >> 50) | (bnzy << 14));
      const int e_cpe = e_mb ? __builtin_ctz(e_mb) : 25;
      if (g4 == e) { iglo = e_iglo; ighi = e_ighi; oglo = e_oglo; oghi = e_oghi; cpe_sel = e_cpe; }
    }

    // ---- softmax: thread-per-(batch, head hh, slot jj) ----
    float ev[7];
    int ig7[7];
    {
      float sv[7];
      float mx = -1e30f;
      const float* sb = stab + cpe_sel * 400 + hh;
#pragma unroll
      for (int m = 0; m < 7; ++m) {
        const int ij = jj + 4 * m;
        if (ij < 25) {
          const int ig = ((iglo >> ij) & 1) | (((ighi >> ij) & 1) << 1);
          ig7[m] = ig;
          sv[m] = sb[ig * 100 + ij * 4];
          mx = fmaxf(mx, sv[m]);
        }
      }
      mx = fmaxf(mx, __shfl_xor(mx, 1));
      mx = fmaxf(mx, __shfl_xor(mx, 2));
      float sum = 0.f;
#pragma unroll
      for (int m = 0; m < 7; ++m) {
        const int ij = jj + 4 * m;
        if (ij < 25) { ev[m] = __expf(sv[m] - mx); sum += ev[m]; }
      }
      sum += __shfl_xor(sum, 1);
      sum += __shfl_xor(sum, 2);
      const float inv = __builtin_amdgcn_rcpf(sum);
#pragma unroll
      for (int m = 0; m < 7; ++m) ev[m] *= inv;
    }

    // ---- scatter W: thread owns k' = 4*(jj+4m)+0..3 (8B each), m=0..6 ----
#pragma unroll
    for (int m = 0; m < 7; ++m) {
      const int ij = jj + 4 * m;
      unsigned u0 = 0, u1 = 0;
      if (ij < 25) {
        const unsigned pbu = (unsigned)(unsigned short)f2bfs(ev[m]);
        const int ig = ig7[m];
        u0 = (ig == 0) ? pbu : ((ig == 1) ? (pbu << 16) : 0u);
        u1 = (ig == 2) ? pbu : ((ig == 3) ? (pbu << 16) : 0u);
      }
      const int off = (hh * 4096 + b_loc * 256 + 8 * ij) ^ bswz;
      *(int2*)((char*)lds_w + off) = make_int2((int)u0, (int)u1);
    }

    // ---- scatter OG row b_loc: thread row16 owns k' = 8*row16..+8 (16B) ----
    {
      unsigned sh[8];
#pragma unroll
      for (int u = 0; u < 8; ++u) {
        const int kp = row16 * 8 + u;
        unsigned v = 0;
        if (kp < 100) {
          const int ijq = kp >> 2;
          const int og = ((oglo >> ijq) & 1) | (((oghi >> ijq) & 1) << 1);
          v = (og == (kp & 3)) ? 0x3F80u : 0u;
        } else if (kp < 126) {
          v = (cpe_sel == kp - 100) ? 0x3F80u : 0u;
        } else if (kp == 126) {
          v = 0x3F80u;
        }
        sh[u] = v;
      }
      int4 pk;
      pk.x = (int)(sh[0] | (sh[1] << 16));
      pk.y = (int)(sh[2] | (sh[3] << 16));
      pk.z = (int)(sh[4] | (sh[5] << 16));
      pk.w = (int)(sh[6] | (sh[7] << 16));
      const int off = (b_loc * 256 + row16 * 16) ^ bswz;
      *(int4*)((char*)lds_og + off) = pk;
    }
    __syncthreads();   // B1: W/OG ready

    // ---- ra-GEMM (W rows = batches, head wv) + pre-GEMM (OG rows) ----
    float4v rc = {0.f, 0.f, 0.f, 0.f};
#pragma unroll
    for (int ks = 0; ks < 4; ++ks) {
      const short8v a = *(const short8v*)((char*)lds_w +
          ((wv * 4096 + row16 * 256 + ks * 64 + g4 * 16) ^ rsw));
      rc = __builtin_amdgcn_mfma_f32_16x16x32_bf16(a, Bv[ks], rc, 0, 0, 0);
    }
    float4v acc[2];
    acc[0] = (float4v){0.f, 0.f, 0.f, 0.f};
    acc[1] = (float4v){0.f, 0.f, 0.f, 0.f};
#pragma unroll
    for (int ks = 0; ks < 4; ++ks) {
      const short8v a = *(const short8v*)((char*)lds_og +
          ((row16 * 256 + ks * 64 + g4 * 16) ^ rsw));
      acc[0] = __builtin_amdgcn_mfma_f32_16x16x32_bf16(a, Bo[0][ks], acc[0], 0, 0, 0);
      acc[1] = __builtin_amdgcn_mfma_f32_16x16x32_bf16(a, Bo[1][ks], acc[1], 0, 0, 0);
    }

    // ---- prefetch next tile's obs (hides HBM latency under MFMA phase) ----
    if (it < 3) {
#pragma unroll
      for (int e = 0; e < 4; ++e) {
        const int* ob = obs + (bbase + (it + 1) * 16 + wv * 4 + e) * 75;
        xs[e] = ob[lane];
        ys[e] = (lane < 11) ? ob[64 + lane] : 0;
      }
    }

    // ---- ra -> LDS (hi only) ----
#pragma unroll
    for (int r = 0; r < 4; ++r) {
      const int b = g4 * 4 + r;
      const int off = (b * 128 + (wv * 16 + row16) * 2) ^ ((b & 7) << 4);
      *(short*)((char*)lds_raH + off) = f2bfs(rc[r]);
    }
    __syncthreads();   // B2: ra ready; W/OG reads done

    // ---- wov-GEMM ----
    const short8v aH0 = *(const short8v*)((char*)lds_raH + ((row16 * 128 + g4 * 16) ^ rsw));
    const short8v aH1 = *(const short8v*)((char*)lds_raH + ((row16 * 128 + 64 + g4 * 16) ^ rsw));
#pragma unroll
    for (int t = 0; t < 2; ++t) {
      acc[t] = __builtin_amdgcn_mfma_f32_16x16x32_bf16(aH0, Bw[t][0], acc[t], 0, 0, 0);
      acc[t] = __builtin_amdgcn_mfma_f32_16x16x32_bf16(aH1, Bw[t][1], acc[t], 0, 0, 0);
    }

    // ---- relu -> hidden bf16 hi+lo ----
#pragma unroll
    for (int t = 0; t < 2; ++t) {
      const int col = wv * 32 + t * 16 + row16;
#pragma unroll
      for (int rr = 0; rr < 4; ++rr) {
        const int row = g4 * 4 + rr;
        const float hv = fmaxf(acc[t][rr], 0.f);
        const short hb = f2bfs(hv);
        const int off = (row * 256 + col * 2) ^ ((row & 7) << 4);
        *(short*)((char*)lds_hidH + off) = hb;
        *(short*)((char*)lds_hidL + off) = f2bfs(hv - bfs2f(hb));
      }
    }
    __syncthreads();   // B3: hidden ready

    // ---- out-GEMM ----
    short8v ahH[4], ahL[4];
#pragma unroll
    for (int ks = 0; ks < 4; ++ks) {
      const int off = (row16 * 256 + ks * 64 + g4 * 16) ^ rsw;
      ahH[ks] = *(const short8v*)((char*)lds_hidH + off);
      ahL[ks] = *(const short8v*)((char*)lds_hidL + off);
    }
#pragma unroll
    for (int t = 0; t < 2; ++t) {
      const int col = wv * 32 + t * 16 + row16;
      float4v c2 = {0.f, 0.f, 0.f, 0.f};
#pragma unroll
      for (int ks = 0; ks < 4; ++ks) {
        c2 = __builtin_amdgcn_mfma_f32_16x16x32_bf16(ahL[ks], Bc[t][ks], c2, 0, 0, 0);
        c2 = __builtin_amdgcn_mfma_f32_16x16x32_bf16(ahH[ks], Bc[t][ks], c2, 0, 0, 0);
      }
      const float bv = t ? bv1 : bv0;
#pragma unroll
      for (int rr = 0; rr < 4; ++rr)
        out[(b0 + g4 * 4 + rr) * 128 + col] = c2[rr] + bv;
    }
  }
}

extern "C" void kernel_launch(void* const* d_in, const int* in_sizes, int n_in,
                              void* d_out, int out_size, void* d_ws, size_t ws_size,
                              hipStream_t stream) {
  const int*   obs         = (const int*)d_in[0];
  const float* color_embed = (const float*)d_in[1];
  const float* row_embed   = (const float*)d_in[2];
  const float* col_embed   = (const float*)d_in[3];
  const float* ip_w1 = (const float*)d_in[4];
  const float* ip_b1 = (const float*)d_in[5];
  const float* ip_w2 = (const float*)d_in[6];
  const float* ip_b2 = (const float*)d_in[7];
  const float* q_w = (const float*)d_in[8];
  const float* q_b = (const float*)d_in[9];
  const float* k_w = (const float*)d_in[10];
  const float* k_b = (const float*)d_in[11];
  const float* v_w = (const float*)d_in[12];
  const float* v_b = (const float*)d_in[13];
  const float* o_w = (const float*)d_in[14];
  const float* o_b = (const float*)d_in[15];
  const float* op_w1 = (const float*)d_in[16];
  const float* op_b1 = (const float*)d_in[17];
  const float* op_w2 = (const float*)d_in[18];
  const float* op_b2 = (const float*)d_in[19];
  const float* cb_w1 = (const float*)d_in[20];
  const float* cb_b1 = (const float*)d_in[21];
  const float* cb_w2 = (const float*)d_in[22];
  const float* cb_b2 = (const float*)d_in[23];

  float* ws = (float*)d_ws;
  float* qtab    = ws;                 // 1664
  float* cpeproj = qtab + 1664;        // 3328
  float* bias1   = cpeproj + 3328;     // 128
  float* stab    = bias1 + 128;        // 10400  (ends at 15520)
  unsigned short* wovT      = (unsigned short*)(ws + 15520);  //  8192 us (4096 f)
  unsigned short* cbw2T     = (unsigned short*)(ws + 19616);  // 16384 us (8192 f)
  unsigned short* vtabT     = (unsigned short*)(ws + 27808);  //  8192 us (4096 f)
  unsigned short* outprojBT = (unsigned short*)(ws + 31904);  // 16384 us (8192 f)
  float* inpval  = ws + 40096;         // 6400
  float* outval  = inpval + 6400;      // 6400
  // total 52896 floats ~= 212 KB of d_ws

  prepA<<<210, 128, 0, stream>>>(color_embed, row_embed, col_embed,
                                 ip_w1, ip_b1, ip_w2, ip_b2,
                                 op_w1, op_b1, op_w2, op_b2,
                                 q_w, q_b, o_w, o_b, cb_w1, cb_b1, cb_w2,
                                 inpval, outval, qtab, cpeproj, bias1,
                                 wovT, cbw2T);
  prepM<<<102, 128, 0, stream>>>(k_w, k_b, v_w, v_b, cb_w1,
                                 qtab, cpeproj, bias1, inpval, outval,
                                 stab, vtabT, outprojBT);
  arc_fused<<<512, 256, 0, stream>>>(obs, stab, vtabT, outprojBT,
                                     wovT, cbw2T, cb_b2, (float*)d_out);
}

// Round 12
// 40.285 us; speedup vs baseline: 1.6882x; 1.5063x over previous
//
#include <hip/hip_runtime.h>
#include <hip/hip_bf16.h>

// PositionAwareARCEncoder fused kernels.
// B=32768, H=W=5, NC=4, E=64, HID=128, OUT=128, NH=4, HD=16.
//
// R11 = R8 revert (proven 39.6 us: flat 3-launch preps + 512x4-tile arc_fused)
//       + software-pipelined decode/softmax (tile i+1's stab gathers issue
//       during tile i's MFMA phase; numerics identical).

typedef __attribute__((ext_vector_type(8))) short short8v;
typedef __attribute__((ext_vector_type(4))) float float4v;

static __device__ __forceinline__ short f2bfs(float f) {
  __hip_bfloat16 h = __float2bfloat16(f);   // native cvt, RNE
  return *reinterpret_cast<short*>(&h);
}
static __device__ __forceinline__ float bfs2f(short s) {
  return __uint_as_float(((unsigned)(unsigned short)s) << 16);
}
static __device__ __forceinline__ unsigned short f2bf(float f) {
  unsigned int u = __float_as_uint(f);
  unsigned int r = (u + 0x7fffu + ((u >> 16) & 1u)) >> 16;
  return (unsigned short)r;
}

__global__ void prep12(const float* __restrict__ color_embed,
                       const float* __restrict__ row_embed,
                       const float* __restrict__ col_embed,
                       const float* __restrict__ ip_w1, const float* __restrict__ ip_b1,
                       const float* __restrict__ ip_w2, const float* __restrict__ ip_b2,
                       const float* __restrict__ op_w1, const float* __restrict__ op_b1,
                       const float* __restrict__ op_w2, const float* __restrict__ op_b2,
                       float* __restrict__ inpval, float* __restrict__ outval) {
  __shared__ float feat[128];
  __shared__ float h1[128];
  const int bid = blockIdx.x;       // 0..199
  const int path = bid / 100;
  const int cij = bid % 100;
  const int c = cij / 25, ij = cij % 25, gi = ij / 5, gj = ij % 5;
  const int t = threadIdx.x;        // 128 threads
  if (t < 64)      feat[t] = color_embed[c * 64 + t];
  else if (t < 96) feat[t] = row_embed[gi * 32 + (t - 64)];
  else             feat[t] = col_embed[gj * 32 + (t - 96)];
  __syncthreads();
  const float* w1 = path ? op_w1 : ip_w1;
  const float* b1 = path ? op_b1 : ip_b1;
  float acc = b1[t];
#pragma unroll 8
  for (int d = 0; d < 128; ++d) acc = fmaf(feat[d], w1[d * 128 + t], acc);
  h1[t] = fmaxf(acc, 0.f);
  __syncthreads();
  if (t < 64) {
    const float* w2 = path ? op_w2 : ip_w2;
    const float* b2 = path ? op_b2 : ip_b2;
    float v = b2[t];
#pragma unroll 8
    for (int d = 0; d < 128; ++d) v = fmaf(h1[d], w2[d * 64 + t], v);
    (path ? outval : inpval)[cij * 64 + t] = v;
  }
}

__global__ void prep3(const float* __restrict__ row_embed, const float* __restrict__ col_embed,
                      const float* __restrict__ k_w, const float* __restrict__ k_b,
                      const float* __restrict__ v_w, const float* __restrict__ v_b,
                      const float* __restrict__ q_w, const float* __restrict__ q_b,
                      const float* __restrict__ o_w, const float* __restrict__ o_b,
                      const float* __restrict__ cb_w1, const float* __restrict__ cb_b1,
                      const float* __restrict__ inpval, const float* __restrict__ outval,
                      float* __restrict__ ktab, float* __restrict__ vtab,
                      float* __restrict__ outproj, float* __restrict__ qtab,
                      float* __restrict__ cpeproj, float* __restrict__ wov,
                      float* __restrict__ bias1) {
  const int tid = blockIdx.x * 256 + threadIdx.x;
  if (tid < 6400) {                       // ktab[100][64]
    const int cij = tid >> 6, e2 = tid & 63;
    const float* x = inpval + cij * 64;
    float a = k_b[e2];
#pragma unroll 8
    for (int e = 0; e < 64; ++e) a = fmaf(x[e], k_w[e * 64 + e2], a);
    ktab[tid] = a;
  } else if (tid < 12800) {               // vtab[100][64]
    const int l = tid - 6400;
    const int cij = l >> 6, e2 = l & 63;
    const float* x = inpval + cij * 64;
    float a = v_b[e2];
#pragma unroll 8
    for (int e = 0; e < 64; ++e) a = fmaf(x[e], v_w[e * 64 + e2], a);
    vtab[l] = a;
  } else if (tid < 25600) {               // outproj[100][128] (1/25 folded)
    const int l = tid - 12800;
    const int cij = l >> 7, jj = l & 127;
    const float* x = outval + cij * 64;
    float a = 0.f;
#pragma unroll 8
    for (int e = 0; e < 64; ++e) a = fmaf(x[e], cb_w1[(64 + e) * 128 + jj], a);
    outproj[l] = a * (1.f / 25.f);
  } else if (tid < 27264) {               // qtab[26][64]
    const int l = tid - 25600;
    const int p = l >> 6, e2 = l & 63;
    float a = q_b[e2];
    if (p < 25) {
      const int r = p / 5, c = p % 5;
#pragma unroll 8
      for (int e = 0; e < 32; ++e) a = fmaf(row_embed[r * 32 + e], q_w[e * 64 + e2], a);
#pragma unroll 8
      for (int e = 0; e < 32; ++e) a = fmaf(col_embed[c * 32 + e], q_w[(32 + e) * 64 + e2], a);
    }
    qtab[l] = a;
  } else if (tid < 30592) {               // cpeproj[26][128]
    const int l = tid - 27264;
    const int p = l >> 7, jj = l & 127;
    float a = 0.f;
    if (p < 25) {
      const int r = p / 5, c = p % 5;
#pragma unroll 8
      for (int e = 0; e < 32; ++e) a = fmaf(row_embed[r * 32 + e], cb_w1[(128 + e) * 128 + jj], a);
#pragma unroll 8
      for (int e = 0; e < 32; ++e) a = fmaf(col_embed[c * 32 + e], cb_w1[(160 + e) * 128 + jj], a);
    }
    cpeproj[l] = a;
  } else if (tid < 38784) {               // wov[64][128]
    const int l = tid - 30592;
    const int d = l >> 7, jj = l & 127;
    float a = 0.f;
#pragma unroll 8
    for (int e = 0; e < 64; ++e) a = fmaf(o_w[d * 64 + e], cb_w1[e * 128 + jj], a);
    wov[l] = a;
  } else if (tid < 38912) {               // bias1[128]
    const int jj = tid - 38784;
    float a = cb_b1[jj];
#pragma unroll 8
    for (int e = 0; e < 64; ++e) a = fmaf(o_b[e], cb_w1[e * 128 + jj], a);
    bias1[jj] = a;
  }
}

// stab + bf16 B-matrices (after prep3). vtabT/outprojBT use k' = 4*ij + sel.
__global__ void prepC(const float* __restrict__ qtab, const float* __restrict__ ktab,
                      const float* __restrict__ wov, const float* __restrict__ cb_w2,
                      const float* __restrict__ outproj, const float* __restrict__ vtab,
                      const float* __restrict__ cpeproj, const float* __restrict__ bias1,
                      float* __restrict__ stab, unsigned short* __restrict__ wovT,
                      unsigned short* __restrict__ cbw2T,
                      unsigned short* __restrict__ vtabT,
                      unsigned short* __restrict__ outprojBT) {
  const int tid = blockIdx.x * 256 + threadIdx.x;
  if (tid < 10400) {                         // stab[cpe][ig][ij][h]
    const int h = tid & 3;
    const int ij = (tid >> 2) % 25;
    const int ig = ((tid >> 2) / 25) & 3;
    const int cpe = (tid >> 2) / 100;
    const float* qq = qtab + cpe * 64 + h * 16;
    const float* kk = ktab + (ig * 25 + ij) * 64 + h * 16;
    float a = 0.f;
#pragma unroll
    for (int d = 0; d < 16; ++d) a = fmaf(qq[d], kk[d], a);
    stab[tid] = a * 0.25f;
  } else if (tid < 18592) {                  // wovT[col 128][k 64]
    const int i = tid - 10400;
    const int j = i >> 6, d = i & 63;
    wovT[i] = f2bf(wov[d * 128 + j]);
  } else if (tid < 34976) {                  // cbw2T[col 128][k 128]
    const int i = tid - 18592;
    const int j = i >> 7, k = i & 127;
    cbw2T[i] = f2bf(cb_w2[k * 128 + j]);
  } else if (tid < 43168) {                  // vtabT[h 4][d 16][k' 128], k'=4ij+ig
    const int i = tid - 34976;
    const int h = i >> 11, rest = i & 2047;
    const int d = rest >> 7, kp = rest & 127;
    const int ij = kp >> 2, ig = kp & 3;
    vtabT[i] = (ij < 25) ? f2bf(vtab[(ig * 25 + ij) * 64 + h * 16 + d]) : 0;
  } else if (tid < 59552) {                  // outprojBT[col 128][k' 128]
    const int i = tid - 43168;
    const int col = i >> 7, kp = i & 127;
    unsigned short v = 0;
    if (kp < 100) {
      const int ij = kp >> 2, og = kp & 3;
      v = f2bf(outproj[(og * 25 + ij) * 128 + col]);
    } else if (kp < 126) {
      v = f2bf(cpeproj[(kp - 100) * 128 + col]);
    } else if (kp == 126) {
      v = f2bf(bias1[col]);
    }
    outprojBT[i] = v;
  }
}

__global__ __launch_bounds__(256) void arc_fused(
    const int* __restrict__ obs,
    const float* __restrict__ stab,
    const unsigned short* __restrict__ vtabT,
    const unsigned short* __restrict__ outprojBT,
    const unsigned short* __restrict__ wovT,
    const unsigned short* __restrict__ cbw2T,
    const float* __restrict__ cb_b2,
    float* __restrict__ out) {
  __shared__ __align__(16) short lds_w[4 * 16 * 128];    // 16 KB, swz by batch row
  __shared__ __align__(16) short lds_og[16 * 128];       // 4 KB
  __shared__ __align__(16) short lds_raH[16 * 64];       // 2 KB
  __shared__ __align__(16) short lds_hidH[16 * 128];     // 4 KB
  __shared__ __align__(16) short lds_hidL[16 * 128];     // 4 KB

  const int tid = threadIdx.x;
  const int lane = tid & 63, wv = tid >> 6;
  const int row16 = lane & 15, g4 = lane >> 4;
  const int hh = row16 >> 2, jj = row16 & 3;
  const int b_loc = wv * 4 + g4;
  const int rsw = (row16 & 7) << 4;
  const int bswz = (b_loc & 7) << 4;
  const int bbase = blockIdx.x * 64;

  // ---- hoist all B-fragments into registers (constant across tiles) ----
  short8v Bv[4], Bo[2][4], Bw[2][2], Bc[2][4];
#pragma unroll
  for (int ks = 0; ks < 4; ++ks)
    Bv[ks] = *(const short8v*)(vtabT + wv * 2048 + row16 * 128 + ks * 32 + g4 * 8);
#pragma unroll
  for (int t = 0; t < 2; ++t) {
    const int col = wv * 32 + t * 16 + row16;
#pragma unroll
    for (int ks = 0; ks < 4; ++ks) {
      Bo[t][ks] = *(const short8v*)(outprojBT + col * 128 + ks * 32 + g4 * 8);
      Bc[t][ks] = *(const short8v*)(cbw2T + col * 128 + ks * 32 + g4 * 8);
    }
#pragma unroll
    for (int ks = 0; ks < 2; ++ks)
      Bw[t][ks] = *(const short8v*)(wovT + col * 64 + ks * 32 + g4 * 8);
  }
  const float bv0 = cb_b2[wv * 32 + row16];
  const float bv1 = cb_b2[wv * 32 + 16 + row16];

  // ---- one-time zero of W (covers the never-scattered pad bytes) ----
  {
    const int4 z = {0, 0, 0, 0};
    int4* pw = (int4*)lds_w;
#pragma unroll
    for (int i = 0; i < 4; ++i) pw[tid + 256 * i] = z;
  }

  // ---- pipelined per-thread softmax state (for the next tile to scatter) ----
  int xs[4], ys[4];
  float ev[7];
  unsigned igp = 0, oglo = 0, oghi = 0;
  int cpe_sel = 0;

  auto load_obs = [&](int t) {
#pragma unroll
    for (int e = 0; e < 4; ++e) {
      const int* ob = obs + (bbase + t * 16 + wv * 4 + e) * 75;
      xs[e] = ob[lane];
      ys[e] = (lane < 11) ? ob[64 + lane] : 0;
    }
  };

  auto decode_softmax = [&]() {
    unsigned iglo_ = 0, ighi_ = 0;
    oglo = 0; oghi = 0; cpe_sel = 0;
#pragma unroll
    for (int e = 0; e < 4; ++e) {
      const unsigned long long blo = __ballot(xs[e] & 1);
      const unsigned long long bhi = __ballot(xs[e] & 2);
      const unsigned long long bnzy = __ballot((lane < 11) && (ys[e] != 0));
      const unsigned e_iglo = (unsigned)(blo & 0x1FFFFFFull);
      const unsigned e_ighi = (unsigned)(bhi & 0x1FFFFFFull);
      const unsigned e_oglo = (unsigned)((blo >> 25) & 0x1FFFFFFull);
      const unsigned e_oghi = (unsigned)((bhi >> 25) & 0x1FFFFFFull);
      const unsigned e_mb = (unsigned)(((blo | bhi) >> 50) | (bnzy << 14));
      const int e_cpe = e_mb ? __builtin_ctz(e_mb) : 25;
      if (g4 == e) { iglo_ = e_iglo; ighi_ = e_ighi; oglo = e_oglo; oghi = e_oghi; cpe_sel = e_cpe; }
    }
    float sv[7];
    float mx = -1e30f;
    igp = 0;
    const float* sb = stab + cpe_sel * 400 + hh;
#pragma unroll
    for (int m = 0; m < 7; ++m) {
      const int ij = jj + 4 * m;
      if (ij < 25) {
        const int ig = ((iglo_ >> ij) & 1) | (((ighi_ >> ij) & 1) << 1);
        igp |= (unsigned)ig << (2 * m);
        sv[m] = sb[ig * 100 + ij * 4];
        mx = fmaxf(mx, sv[m]);
      }
    }
    mx = fmaxf(mx, __shfl_xor(mx, 1));
    mx = fmaxf(mx, __shfl_xor(mx, 2));
    float sum = 0.f;
#pragma unroll
    for (int m = 0; m < 7; ++m) {
      const int ij = jj + 4 * m;
      if (ij < 25) { ev[m] = __expf(sv[m] - mx); sum += ev[m]; }
    }
    sum += __shfl_xor(sum, 1);
    sum += __shfl_xor(sum, 2);
    const float inv = __builtin_amdgcn_rcpf(sum);
#pragma unroll
    for (int m = 0; m < 7; ++m) ev[m] *= inv;
  };

  // prologue: obs(0) -> decode/softmax(0) -> obs(1)
  load_obs(0);
  __syncthreads();   // W zero visible to all (overlaps obs load latency)
  decode_softmax();
  load_obs(1);

  for (int it = 0; it < 4; ++it) {
    const int b0 = bbase + it * 16;

    // ---- scatter W: thread owns k' = 4*(jj+4m)+0..3 (8B each), m=0..6 ----
#pragma unroll
    for (int m = 0; m < 7; ++m) {
      const int ij = jj + 4 * m;
      unsigned u0 = 0, u1 = 0;
      if (ij < 25) {
        const unsigned pbu = (unsigned)(unsigned short)f2bfs(ev[m]);
        const int ig = (int)((igp >> (2 * m)) & 3u);
        u0 = (ig == 0) ? pbu : ((ig == 1) ? (pbu << 16) : 0u);
        u1 = (ig == 2) ? pbu : ((ig == 3) ? (pbu << 16) : 0u);
      }
      const int off = (hh * 4096 + b_loc * 256 + 8 * ij) ^ bswz;
      *(int2*)((char*)lds_w + off) = make_int2((int)u0, (int)u1);
    }

    // ---- scatter OG row b_loc: thread row16 owns k' = 8*row16..+8 (16B) ----
    {
      unsigned sh[8];
#pragma unroll
      for (int u = 0; u < 8; ++u) {
        const int kp = row16 * 8 + u;
        unsigned v = 0;
        if (kp < 100) {
          const int ijq = kp >> 2;
          const int og = ((oglo >> ijq) & 1) | (((oghi >> ijq) & 1) << 1);
          v = (og == (kp & 3)) ? 0x3F80u : 0u;
        } else if (kp < 126) {
          v = (cpe_sel == kp - 100) ? 0x3F80u : 0u;
        } else if (kp == 126) {
          v = 0x3F80u;
        }
        sh[u] = v;
      }
      int4 pk;
      pk.x = (int)(sh[0] | (sh[1] << 16));
      pk.y = (int)(sh[2] | (sh[3] << 16));
      pk.z = (int)(sh[4] | (sh[5] << 16));
      pk.w = (int)(sh[6] | (sh[7] << 16));
      const int off = (b_loc * 256 + row16 * 16) ^ bswz;
      *(int4*)((char*)lds_og + off) = pk;
    }
    __syncthreads();   // B1: W/OG ready

    // ---- ra-GEMM (W rows = batches, head wv) + pre-GEMM (OG rows) ----
    float4v rc = {0.f, 0.f, 0.f, 0.f};
#pragma unroll
    for (int ks = 0; ks < 4; ++ks) {
      const short8v a = *(const short8v*)((char*)lds_w +
          ((wv * 4096 + row16 * 256 + ks * 64 + g4 * 16) ^ rsw));
      rc = __builtin_amdgcn_mfma_f32_16x16x32_bf16(a, Bv[ks], rc, 0, 0, 0);
    }
    float4v acc[2];
    acc[0] = (float4v){0.f, 0.f, 0.f, 0.f};
    acc[1] = (float4v){0.f, 0.f, 0.f, 0.f};
#pragma unroll
    for (int ks = 0; ks < 4; ++ks) {
      const short8v a = *(const short8v*)((char*)lds_og +
          ((row16 * 256 + ks * 64 + g4 * 16) ^ rsw));
      acc[0] = __builtin_amdgcn_mfma_f32_16x16x32_bf16(a, Bo[0][ks], acc[0], 0, 0, 0);
      acc[1] = __builtin_amdgcn_mfma_f32_16x16x32_bf16(a, Bo[1][ks], acc[1], 0, 0, 0);
    }

    // ---- pipeline: decode+softmax for tile it+1 (stab gathers overlap the
    //      remaining MFMA phases/barriers); then prefetch obs for it+2 ----
    if (it < 3) {
      decode_softmax();
      if (it < 2) load_obs(it + 2);
    }

    // ---- ra -> LDS (hi only) ----
#pragma unroll
    for (int r = 0; r < 4; ++r) {
      const int b = g4 * 4 + r;
      const int off = (b * 128 + (wv * 16 + row16) * 2) ^ ((b & 7) << 4);
      *(short*)((char*)lds_raH + off) = f2bfs(rc[r]);
    }
    __syncthreads();   // B2: ra ready; W/OG reads done

    // ---- wov-GEMM ----
    const short8v aH0 = *(const short8v*)((char*)lds_raH + ((row16 * 128 + g4 * 16) ^ rsw));
    const short8v aH1 = *(const short8v*)((char*)lds_raH + ((row16 * 128 + 64 + g4 * 16) ^ rsw));
#pragma unroll
    for (int t = 0; t < 2; ++t) {
      acc[t] = __builtin_amdgcn_mfma_f32_16x16x32_bf16(aH0, Bw[t][0], acc[t], 0, 0, 0);
      acc[t] = __builtin_amdgcn_mfma_f32_16x16x32_bf16(aH1, Bw[t][1], acc[t], 0, 0, 0);
    }

    // ---- relu -> hidden bf16 hi+lo ----
#pragma unroll
    for (int t = 0; t < 2; ++t) {
      const int col = wv * 32 + t * 16 + row16;
#pragma unroll
      for (int rr = 0; rr < 4; ++rr) {
        const int row = g4 * 4 + rr;
        const float hv = fmaxf(acc[t][rr], 0.f);
        const short hb = f2bfs(hv);
        const int off = (row * 256 + col * 2) ^ ((row & 7) << 4);
        *(short*)((char*)lds_hidH + off) = hb;
        *(short*)((char*)lds_hidL + off) = f2bfs(hv - bfs2f(hb));
      }
    }
    __syncthreads();   // B3: hidden ready

    // ---- out-GEMM ----
    short8v ahH[4], ahL[4];
#pragma unroll
    for (int ks = 0; ks < 4; ++ks) {
      const int off = (row16 * 256 + ks * 64 + g4 * 16) ^ rsw;
      ahH[ks] = *(const short8v*)((char*)lds_hidH + off);
      ahL[ks] = *(const short8v*)((char*)lds_hidL + off);
    }
#pragma unroll
    for (int t = 0; t < 2; ++t) {
      const int col = wv * 32 + t * 16 + row16;
      float4v c2 = {0.f, 0.f, 0.f, 0.f};
#pragma unroll
      for (int ks = 0; ks < 4; ++ks) {
        c2 = __builtin_amdgcn_mfma_f32_16x16x32_bf16(ahL[ks], Bc[t][ks], c2, 0, 0, 0);
        c2 = __builtin_amdgcn_mfma_f32_16x16x32_bf16(ahH[ks], Bc[t][ks], c2, 0, 0, 0);
      }
      const float bv = t ? bv1 : bv0;
#pragma unroll
      for (int rr = 0; rr < 4; ++rr)
        out[(b0 + g4 * 4 + rr) * 128 + col] = c2[rr] + bv;
    }
  }
}

extern "C" void kernel_launch(void* const* d_in, const int* in_sizes, int n_in,
                              void* d_out, int out_size, void* d_ws, size_t ws_size,
                              hipStream_t stream) {
  const int*   obs         = (const int*)d_in[0];
  const float* color_embed = (const float*)d_in[1];
  const float* row_embed   = (const float*)d_in[2];
  const float* col_embed   = (const float*)d_in[3];
  const float* ip_w1 = (const float*)d_in[4];
  const float* ip_b1 = (const float*)d_in[5];
  const float* ip_w2 = (const float*)d_in[6];
  const float* ip_b2 = (const float*)d_in[7];
  const float* q_w = (const float*)d_in[8];
  const float* q_b = (const float*)d_in[9];
  const float* k_w = (const float*)d_in[10];
  const float* k_b = (const float*)d_in[11];
  const float* v_w = (const float*)d_in[12];
  const float* v_b = (const float*)d_in[13];
  const float* o_w = (const float*)d_in[14];
  const float* o_b = (const float*)d_in[15];
  const float* op_w1 = (const float*)d_in[16];
  const float* op_b1 = (const float*)d_in[17];
  const float* op_w2 = (const float*)d_in[18];
  const float* op_b2 = (const float*)d_in[19];
  const float* cb_w1 = (const float*)d_in[20];
  const float* cb_b1 = (const float*)d_in[21];
  const float* cb_w2 = (const float*)d_in[22];
  const float* cb_b2 = (const float*)d_in[23];

  float* ws = (float*)d_ws;
  float* qtab    = ws;                 // 1664
  float* cpeproj = qtab + 1664;        // 3328
  float* ktab    = cpeproj + 3328;     // 6400
  float* vtab    = ktab + 6400;        // 6400
  float* outproj = vtab + 6400;        // 12800
  float* wov     = outproj + 12800;    // 8192
  float* bias1   = wov + 8192;         // 128
  float* stab    = bias1 + 128;        // 10400  (ends at 49312)
  unsigned short* wovT      = (unsigned short*)(ws + 49312);  //  8192 us (4096 f)
  unsigned short* cbw2T     = (unsigned short*)(ws + 53408);  // 16384 us (8192 f)
  unsigned short* vtabT     = (unsigned short*)(ws + 61600);  //  8192 us (4096 f)
  unsigned short* outprojBT = (unsigned short*)(ws + 65696);  // 16384 us (8192 f)
  float* inpval  = ws + 73888;         // 6400
  float* outval  = inpval + 6400;      // 6400
  // total 86688 floats ~= 347 KB of d_ws

  prep12<<<200, 128, 0, stream>>>(color_embed, row_embed, col_embed,
                                  ip_w1, ip_b1, ip_w2, ip_b2,
                                  op_w1, op_b1, op_w2, op_b2, inpval, outval);
  prep3<<<152, 256, 0, stream>>>(row_embed, col_embed, k_w, k_b, v_w, v_b,
                                 q_w, q_b, o_w, o_b, cb_w1, cb_b1,
                                 inpval, outval,
                                 ktab, vtab, outproj, qtab, cpeproj, wov, bias1);
  prepC<<<233, 256, 0, stream>>>(qtab, ktab, wov, cb_w2, outproj, vtab,
                                 cpeproj, bias1,
                                 stab, wovT, cbw2T, vtabT, outprojBT);
  arc_fused<<<512, 256, 0, stream>>>(obs, stab, vtabT, outprojBT,
                                     wovT, cbw2T, cb_b2, (float*)d_out);
}

// Round 13
// 36.793 us; speedup vs baseline: 1.8484x; 1.0949x over previous
//
#include <hip/hip_runtime.h>
#include <hip/hip_bf16.h>

// PositionAwareARCEncoder fused kernels.
// B=32768, H=W=5, NC=4, E=64, HID=128, OUT=128, NH=4, HD=16.
//
// R12: prep chain consolidated to 2 launches, every section in flat shape
// (<=64-FMA-per-thread one-output-per-thread, or per-cij blocks with
// block-local LDS dep). arc_fused = R8's proven kernel verbatim.
//
//  prepE (432 blocks x 128): MLPs (200 blocks) + flat qtab/cpeproj/bias1/
//    wovT (o_w@cb_w1 fused to bf16) / cbw2T.
//  prepF (101 blocks x 256): per-cij: k-col -> LDS -> stab slice; v-col ->
//    vtabT (k'=4ij+ig); outproj-col -> outprojBT. Aux block: cpe/bias rows
//    + vtabT pad zeros.

typedef __attribute__((ext_vector_type(8))) short short8v;
typedef __attribute__((ext_vector_type(4))) float float4v;

static __device__ __forceinline__ short f2bfs(float f) {
  __hip_bfloat16 h = __float2bfloat16(f);   // native cvt, RNE
  return *reinterpret_cast<short*>(&h);
}
static __device__ __forceinline__ float bfs2f(short s) {
  return __uint_as_float(((unsigned)(unsigned short)s) << 16);
}
static __device__ __forceinline__ unsigned short f2bf(float f) {
  unsigned int u = __float_as_uint(f);
  unsigned int r = (u + 0x7fffu + ((u >> 16) & 1u)) >> 16;
  return (unsigned short)r;
}

// ---------------- prepE: MLPs + all MLP-independent tables (flat) ---------
__global__ __launch_bounds__(128) void prepE(
    const float* __restrict__ color_embed, const float* __restrict__ row_embed,
    const float* __restrict__ col_embed,
    const float* __restrict__ ip_w1, const float* __restrict__ ip_b1,
    const float* __restrict__ ip_w2, const float* __restrict__ ip_b2,
    const float* __restrict__ op_w1, const float* __restrict__ op_b1,
    const float* __restrict__ op_w2, const float* __restrict__ op_b2,
    const float* __restrict__ q_w, const float* __restrict__ q_b,
    const float* __restrict__ o_w, const float* __restrict__ o_b,
    const float* __restrict__ cb_w1, const float* __restrict__ cb_b1,
    const float* __restrict__ cb_w2,
    float* __restrict__ inpval, float* __restrict__ outval,
    float* __restrict__ qtab, float* __restrict__ cpeproj,
    float* __restrict__ bias1,
    unsigned short* __restrict__ wovT, unsigned short* __restrict__ cbw2T) {
  const int bid = blockIdx.x, t = threadIdx.x;
  if (bid < 200) {                         // MLP for cij (input / output path)
    __shared__ float feat[128];
    __shared__ float h1[128];
    const int path = bid / 100;
    const int cij = bid % 100;
    const int c = cij / 25, ij = cij % 25, gi = ij / 5, gj = ij % 5;
    if (t < 64)      feat[t] = color_embed[c * 64 + t];
    else if (t < 96) feat[t] = row_embed[gi * 32 + (t - 64)];
    else             feat[t] = col_embed[gj * 32 + (t - 96)];
    __syncthreads();
    const float* w1 = path ? op_w1 : ip_w1;
    const float* b1 = path ? op_b1 : ip_b1;
    float acc = b1[t];
#pragma unroll 8
    for (int d = 0; d < 128; ++d) acc = fmaf(feat[d], w1[d * 128 + t], acc);
    h1[t] = fmaxf(acc, 0.f);
    __syncthreads();
    if (t < 64) {
      const float* w2 = path ? op_w2 : ip_w2;
      const float* b2 = path ? op_b2 : ip_b2;
      float v = b2[t];
#pragma unroll 8
      for (int d = 0; d < 128; ++d) v = fmaf(h1[d], w2[d * 64 + t], v);
      (path ? outval : inpval)[cij * 64 + t] = v;
    }
    return;
  }
  // flat one-output-per-thread sections
  const int fid = (bid - 200) * 128 + t;
  if (fid < 1664) {                        // qtab[26][64]
    const int p = fid >> 6, e2 = fid & 63;
    float a = q_b[e2];
    if (p < 25) {
      const int r = p / 5, cc = p % 5;
#pragma unroll 8
      for (int e = 0; e < 32; ++e) a = fmaf(row_embed[r * 32 + e], q_w[e * 64 + e2], a);
#pragma unroll 8
      for (int e = 0; e < 32; ++e) a = fmaf(col_embed[cc * 32 + e], q_w[(32 + e) * 64 + e2], a);
    }
    qtab[fid] = a;
  } else if (fid < 4992) {                 // cpeproj[26][128]
    const int l = fid - 1664;
    const int p = l >> 7, jj = l & 127;
    float a = 0.f;
    if (p < 25) {
      const int r = p / 5, cc = p % 5;
#pragma unroll 8
      for (int e = 0; e < 32; ++e) a = fmaf(row_embed[r * 32 + e], cb_w1[(128 + e) * 128 + jj], a);
#pragma unroll 8
      for (int e = 0; e < 32; ++e) a = fmaf(col_embed[cc * 32 + e], cb_w1[(160 + e) * 128 + jj], a);
    }
    cpeproj[l] = a;
  } else if (fid < 5120) {                 // bias1[128]
    const int jj = fid - 4992;
    float a = cb_b1[jj];
#pragma unroll 8
    for (int e = 0; e < 64; ++e) a = fmaf(o_b[e], cb_w1[e * 128 + jj], a);
    bias1[jj] = a;
  } else if (fid < 13312) {                // wovT[col 128][d 64] = bf16(o_w@cb_w1)
    const int i = fid - 5120;
    const int col = i >> 6, d = i & 63;
    float a = 0.f;
#pragma unroll 8
    for (int e = 0; e < 64; ++e) a = fmaf(o_w[d * 64 + e], cb_w1[e * 128 + col], a);
    wovT[i] = f2bf(a);
  } else if (fid < 29696) {                // cbw2T[col 128][k 128]
    const int i = fid - 13312;
    const int col = i >> 7, k = i & 127;
    cbw2T[i] = f2bf(cb_w2[k * 128 + col]);
  }
}

// ---------------- prepF: per-cij k/v/outproj + stab; aux rows --------------
__global__ __launch_bounds__(256) void prepF(
    const float* __restrict__ k_w, const float* __restrict__ k_b,
    const float* __restrict__ v_w, const float* __restrict__ v_b,
    const float* __restrict__ cb_w1,
    const float* __restrict__ qtab, const float* __restrict__ cpeproj,
    const float* __restrict__ bias1,
    const float* __restrict__ inpval, const float* __restrict__ outval,
    float* __restrict__ stab, unsigned short* __restrict__ vtabT,
    unsigned short* __restrict__ outprojBT) {
  const int bid = blockIdx.x, t = threadIdx.x;
  if (bid < 100) {
    __shared__ float kk[64];
    const int ig = bid / 25, ij = bid % 25;   // color, cell
    const float* x = inpval + bid * 64;
    if (t < 64) {                            // k column -> LDS
      float a = k_b[t];
#pragma unroll 8
      for (int e = 0; e < 64; ++e) a = fmaf(x[e], k_w[e * 64 + t], a);
      kk[t] = a;
    } else if (t < 128) {                    // v column -> vtabT direct (k'=4ij+ig)
      const int e2 = t - 64;
      float a = v_b[e2];
#pragma unroll 8
      for (int e = 0; e < 64; ++e) a = fmaf(x[e], v_w[e * 64 + e2], a);
      vtabT[(e2 >> 4) * 2048 + (e2 & 15) * 128 + 4 * ij + ig] = f2bf(a);
    } else {                                 // outproj column -> outprojBT direct
      const int col = t - 128;
      const float* y = outval + bid * 64;
      float a = 0.f;
#pragma unroll 8
      for (int e = 0; e < 64; ++e) a = fmaf(y[e], cb_w1[(64 + e) * 128 + col], a);
      outprojBT[col * 128 + 4 * ij + ig] = f2bf(a * (1.f / 25.f));
    }
    __syncthreads();
    if (t < 104) {                           // stab slice for this (ig, ij)
      const int cpe = t >> 2, h = t & 3;
      const float* qq = qtab + cpe * 64 + h * 16;
      float a = 0.f;
#pragma unroll
      for (int d = 0; d < 16; ++d) a = fmaf(qq[d], kk[h * 16 + d], a);
      stab[cpe * 400 + ig * 100 + ij * 4 + h] = a * 0.25f;
    }
  } else {                                   // aux block
    if (t < 128) {                           // outprojBT rows 100..127
      for (int p = 0; p < 26; ++p)
        outprojBT[t * 128 + 100 + p] = f2bf(cpeproj[p * 128 + t]);
      outprojBT[t * 128 + 126] = f2bf(bias1[t]);
      outprojBT[t * 128 + 127] = 0;
    } else {                                 // zero vtabT k' rows 100..127
      for (int i = t - 128; i < 1792; i += 128) {
        const int h = i / 448, r = i % 448;
        const int d = r / 28, kp = 100 + r % 28;
        vtabT[h * 2048 + d * 128 + kp] = 0;
      }
    }
  }
}

// ---------------- arc_fused: R8 proven kernel verbatim --------------------
__global__ __launch_bounds__(256) void arc_fused(
    const int* __restrict__ obs,
    const float* __restrict__ stab,
    const unsigned short* __restrict__ vtabT,
    const unsigned short* __restrict__ outprojBT,
    const unsigned short* __restrict__ wovT,
    const unsigned short* __restrict__ cbw2T,
    const float* __restrict__ cb_b2,
    float* __restrict__ out) {
  __shared__ __align__(16) short lds_w[4 * 16 * 128];    // 16 KB, swz by batch row
  __shared__ __align__(16) short lds_og[16 * 128];       // 4 KB
  __shared__ __align__(16) short lds_raH[16 * 64];       // 2 KB
  __shared__ __align__(16) short lds_hidH[16 * 128];     // 4 KB
  __shared__ __align__(16) short lds_hidL[16 * 128];     // 4 KB

  const int tid = threadIdx.x;
  const int lane = tid & 63, wv = tid >> 6;
  const int row16 = lane & 15, g4 = lane >> 4;
  const int hh = row16 >> 2, jj = row16 & 3;
  const int b_loc = wv * 4 + g4;
  const int rsw = (row16 & 7) << 4;
  const int bswz = (b_loc & 7) << 4;
  const int bbase = blockIdx.x * 64;

  // ---- hoist all B-fragments into registers (constant across tiles) ----
  short8v Bv[4], Bo[2][4], Bw[2][2], Bc[2][4];
#pragma unroll
  for (int ks = 0; ks < 4; ++ks)
    Bv[ks] = *(const short8v*)(vtabT + wv * 2048 + row16 * 128 + ks * 32 + g4 * 8);
#pragma unroll
  for (int t = 0; t < 2; ++t) {
    const int col = wv * 32 + t * 16 + row16;
#pragma unroll
    for (int ks = 0; ks < 4; ++ks) {
      Bo[t][ks] = *(const short8v*)(outprojBT + col * 128 + ks * 32 + g4 * 8);
      Bc[t][ks] = *(const short8v*)(cbw2T + col * 128 + ks * 32 + g4 * 8);
    }
#pragma unroll
    for (int ks = 0; ks < 2; ++ks)
      Bw[t][ks] = *(const short8v*)(wovT + col * 64 + ks * 32 + g4 * 8);
  }
  const float bv0 = cb_b2[wv * 32 + row16];
  const float bv1 = cb_b2[wv * 32 + 16 + row16];

  // ---- one-time zero of W (covers the never-scattered pad bytes) ----
  {
    const int4 z = {0, 0, 0, 0};
    int4* pw = (int4*)lds_w;
#pragma unroll
    for (int i = 0; i < 4; ++i) pw[tid + 256 * i] = z;
  }

  // ---- prefetch obs for tile 0 ----
  int xs[4], ys[4];
#pragma unroll
  for (int e = 0; e < 4; ++e) {
    const int* ob = obs + (bbase + wv * 4 + e) * 75;
    xs[e] = ob[lane];
    ys[e] = (lane < 11) ? ob[64 + lane] : 0;
  }
  __syncthreads();   // W zero visible to all

  for (int it = 0; it < 4; ++it) {
    const int b0 = bbase + it * 16;

    // ---- decode from prefetched obs ----
    unsigned iglo = 0, ighi = 0, oglo = 0, oghi = 0;
    int cpe_sel = 0;
#pragma unroll
    for (int e = 0; e < 4; ++e) {
      const unsigned long long blo = __ballot(xs[e] & 1);
      const unsigned long long bhi = __ballot(xs[e] & 2);
      const unsigned long long bnzy = __ballot((lane < 11) && (ys[e] != 0));
      const unsigned e_iglo = (unsigned)(blo & 0x1FFFFFFull);
      const unsigned e_ighi = (unsigned)(bhi & 0x1FFFFFFull);
      const unsigned e_oglo = (unsigned)((blo >> 25) & 0x1FFFFFFull);
      const unsigned e_oghi = (unsigned)((bhi >> 25) & 0x1FFFFFFull);
      const unsigned e_mb = (unsigned)(((blo | bhi) >> 50) | (bnzy << 14));
      const int e_cpe = e_mb ? __builtin_ctz(e_mb) : 25;
      if (g4 == e) { iglo = e_iglo; ighi = e_ighi; oglo = e_oglo; oghi = e_oghi; cpe_sel = e_cpe; }
    }

    // ---- softmax: thread-per-(batch, head hh, slot jj) ----
    float ev[7];
    int ig7[7];
    {
      float sv[7];
      float mx = -1e30f;
      const float* sb = stab + cpe_sel * 400 + hh;
#pragma unroll
      for (int m = 0; m < 7; ++m) {
        const int ij = jj + 4 * m;
        if (ij < 25) {
          const int ig = ((iglo >> ij) & 1) | (((ighi >> ij) & 1) << 1);
          ig7[m] = ig;
          sv[m] = sb[ig * 100 + ij * 4];
          mx = fmaxf(mx, sv[m]);
        }
      }
      mx = fmaxf(mx, __shfl_xor(mx, 1));
      mx = fmaxf(mx, __shfl_xor(mx, 2));
      float sum = 0.f;
#pragma unroll
      for (int m = 0; m < 7; ++m) {
        const int ij = jj + 4 * m;
        if (ij < 25) { ev[m] = __expf(sv[m] - mx); sum += ev[m]; }
      }
      sum += __shfl_xor(sum, 1);
      sum += __shfl_xor(sum, 2);
      const float inv = __builtin_amdgcn_rcpf(sum);
#pragma unroll
      for (int m = 0; m < 7; ++m) ev[m] *= inv;
    }

    // ---- scatter W: thread owns k' = 4*(jj+4m)+0..3 (8B each), m=0..6 ----
#pragma unroll
    for (int m = 0; m < 7; ++m) {
      const int ij = jj + 4 * m;
      unsigned u0 = 0, u1 = 0;
      if (ij < 25) {
        const unsigned pbu = (unsigned)(unsigned short)f2bfs(ev[m]);
        const int ig = ig7[m];
        u0 = (ig == 0) ? pbu : ((ig == 1) ? (pbu << 16) : 0u);
        u1 = (ig == 2) ? pbu : ((ig == 3) ? (pbu << 16) : 0u);
      }
      const int off = (hh * 4096 + b_loc * 256 + 8 * ij) ^ bswz;
      *(int2*)((char*)lds_w + off) = make_int2((int)u0, (int)u1);
    }

    // ---- scatter OG row b_loc: thread row16 owns k' = 8*row16..+8 (16B) ----
    {
      unsigned sh[8];
#pragma unroll
      for (int u = 0; u < 8; ++u) {
        const int kp = row16 * 8 + u;
        unsigned v = 0;
        if (kp < 100) {
          const int ijq = kp >> 2;
          const int og = ((oglo >> ijq) & 1) | (((oghi >> ijq) & 1) << 1);
          v = (og == (kp & 3)) ? 0x3F80u : 0u;
        } else if (kp < 126) {
          v = (cpe_sel == kp - 100) ? 0x3F80u : 0u;
        } else if (kp == 126) {
          v = 0x3F80u;
        }
        sh[u] = v;
      }
      int4 pk;
      pk.x = (int)(sh[0] | (sh[1] << 16));
      pk.y = (int)(sh[2] | (sh[3] << 16));
      pk.z = (int)(sh[4] | (sh[5] << 16));
      pk.w = (int)(sh[6] | (sh[7] << 16));
      const int off = (b_loc * 256 + row16 * 16) ^ bswz;
      *(int4*)((char*)lds_og + off) = pk;
    }
    __syncthreads();   // B1: W/OG ready

    // ---- ra-GEMM (W rows = batches, head wv) + pre-GEMM (OG rows) ----
    float4v rc = {0.f, 0.f, 0.f, 0.f};
#pragma unroll
    for (int ks = 0; ks < 4; ++ks) {
      const short8v a = *(const short8v*)((char*)lds_w +
          ((wv * 4096 + row16 * 256 + ks * 64 + g4 * 16) ^ rsw));
      rc = __builtin_amdgcn_mfma_f32_16x16x32_bf16(a, Bv[ks], rc, 0, 0, 0);
    }
    float4v acc[2];
    acc[0] = (float4v){0.f, 0.f, 0.f, 0.f};
    acc[1] = (float4v){0.f, 0.f, 0.f, 0.f};
#pragma unroll
    for (int ks = 0; ks < 4; ++ks) {
      const short8v a = *(const short8v*)((char*)lds_og +
          ((row16 * 256 + ks * 64 + g4 * 16) ^ rsw));
      acc[0] = __builtin_amdgcn_mfma_f32_16x16x32_bf16(a, Bo[0][ks], acc[0], 0, 0, 0);
      acc[1] = __builtin_amdgcn_mfma_f32_16x16x32_bf16(a, Bo[1][ks], acc[1], 0, 0, 0);
    }

    // ---- prefetch next tile's obs (hides HBM latency under MFMA phase) ----
    if (it < 3) {
#pragma unroll
      for (int e = 0; e < 4; ++e) {
        const int* ob = obs + (bbase + (it + 1) * 16 + wv * 4 + e) * 75;
        xs[e] = ob[lane];
        ys[e] = (lane < 11) ? ob[64 + lane] : 0;
      }
    }

    // ---- ra -> LDS (hi only) ----
#pragma unroll
    for (int r = 0; r < 4; ++r) {
      const int b = g4 * 4 + r;
      const int off = (b * 128 + (wv * 16 + row16) * 2) ^ ((b & 7) << 4);
      *(short*)((char*)lds_raH + off) = f2bfs(rc[r]);
    }
    __syncthreads();   // B2: ra ready; W/OG reads done

    // ---- wov-GEMM ----
    const short8v aH0 = *(const short8v*)((char*)lds_raH + ((row16 * 128 + g4 * 16) ^ rsw));
    const short8v aH1 = *(const short8v*)((char*)lds_raH + ((row16 * 128 + 64 + g4 * 16) ^ rsw));
#pragma unroll
    for (int t = 0; t < 2; ++t) {
      acc[t] = __builtin_amdgcn_mfma_f32_16x16x32_bf16(aH0, Bw[t][0], acc[t], 0, 0, 0);
      acc[t] = __builtin_amdgcn_mfma_f32_16x16x32_bf16(aH1, Bw[t][1], acc[t], 0, 0, 0);
    }

    // ---- relu -> hidden bf16 hi+lo ----
#pragma unroll
    for (int t = 0; t < 2; ++t) {
      const int col = wv * 32 + t * 16 + row16;
#pragma unroll
      for (int rr = 0; rr < 4; ++rr) {
        const int row = g4 * 4 + rr;
        const float hv = fmaxf(acc[t][rr], 0.f);
        const short hb = f2bfs(hv);
        const int off = (row * 256 + col * 2) ^ ((row & 7) << 4);
        *(short*)((char*)lds_hidH + off) = hb;
        *(short*)((char*)lds_hidL + off) = f2bfs(hv - bfs2f(hb));
      }
    }
    __syncthreads();   // B3: hidden ready

    // ---- out-GEMM ----
    short8v ahH[4], ahL[4];
#pragma unroll
    for (int ks = 0; ks < 4; ++ks) {
      const int off = (row16 * 256 + ks * 64 + g4 * 16) ^ rsw;
      ahH[ks] = *(const short8v*)((char*)lds_hidH + off);
      ahL[ks] = *(const short8v*)((char*)lds_hidL + off);
    }
#pragma unroll
    for (int t = 0; t < 2; ++t) {
      const int col = wv * 32 + t * 16 + row16;
      float4v c2 = {0.f, 0.f, 0.f, 0.f};
#pragma unroll
      for (int ks = 0; ks < 4; ++ks) {
        c2 = __builtin_amdgcn_mfma_f32_16x16x32_bf16(ahL[ks], Bc[t][ks], c2, 0, 0, 0);
        c2 = __builtin_amdgcn_mfma_f32_16x16x32_bf16(ahH[ks], Bc[t][ks], c2, 0, 0, 0);
      }
      const float bv = t ? bv1 : bv0;
#pragma unroll
      for (int rr = 0; rr < 4; ++rr)
        out[(b0 + g4 * 4 + rr) * 128 + col] = c2[rr] + bv;
    }
  }
}

extern "C" void kernel_launch(void* const* d_in, const int* in_sizes, int n_in,
                              void* d_out, int out_size, void* d_ws, size_t ws_size,
                              hipStream_t stream) {
  const int*   obs         = (const int*)d_in[0];
  const float* color_embed = (const float*)d_in[1];
  const float* row_embed   = (const float*)d_in[2];
  const float* col_embed   = (const float*)d_in[3];
  const float* ip_w1 = (const float*)d_in[4];
  const float* ip_b1 = (const float*)d_in[5];
  const float* ip_w2 = (const float*)d_in[6];
  const float* ip_b2 = (const float*)d_in[7];
  const float* q_w = (const float*)d_in[8];
  const float* q_b = (const float*)d_in[9];
  const float* k_w = (const float*)d_in[10];
  const float* k_b = (const float*)d_in[11];
  const float* v_w = (const float*)d_in[12];
  const float* v_b = (const float*)d_in[13];
  const float* o_w = (const float*)d_in[14];
  const float* o_b = (const float*)d_in[15];
  const float* op_w1 = (const float*)d_in[16];
  const float* op_b1 = (const float*)d_in[17];
  const float* op_w2 = (const float*)d_in[18];
  const float* op_b2 = (const float*)d_in[19];
  const float* cb_w1 = (const float*)d_in[20];
  const float* cb_b1 = (const float*)d_in[21];
  const float* cb_w2 = (const float*)d_in[22];
  const float* cb_b2 = (const float*)d_in[23];

  float* ws = (float*)d_ws;
  float* qtab    = ws;                 // 1664
  float* cpeproj = qtab + 1664;        // 3328
  float* bias1   = cpeproj + 3328;     // 128
  float* stab    = bias1 + 128;        // 10400  (ends at 15520)
  unsigned short* wovT      = (unsigned short*)(ws + 15520);  //  8192 us (4096 f)
  unsigned short* cbw2T     = (unsigned short*)(ws + 19616);  // 16384 us (8192 f)
  unsigned short* vtabT     = (unsigned short*)(ws + 27808);  //  8192 us (4096 f)
  unsigned short* outprojBT = (unsigned short*)(ws + 31904);  // 16384 us (8192 f)
  float* inpval  = ws + 40096;         // 6400
  float* outval  = inpval + 6400;      // 6400
  // total 52896 floats ~= 212 KB of d_ws

  prepE<<<432, 128, 0, stream>>>(color_embed, row_embed, col_embed,
                                 ip_w1, ip_b1, ip_w2, ip_b2,
                                 op_w1, op_b1, op_w2, op_b2,
                                 q_w, q_b, o_w, o_b, cb_w1, cb_b1, cb_w2,
                                 inpval, outval, qtab, cpeproj, bias1,
                                 wovT, cbw2T);
  prepF<<<101, 256, 0, stream>>>(k_w, k_b, v_w, v_b, cb_w1,
                                 qtab, cpeproj, bias1, inpval, outval,
                                 stab, vtabT, outprojBT);
  arc_fused<<<512, 256, 0, stream>>>(obs, stab, vtabT, outprojBT,
                                     wovT, cbw2T, cb_b2, (float*)d_out);
}